// Round 1
// baseline (807.579 us; speedup 1.0000x reference)
//
#include <hip/hip_runtime.h>
#include <hip/hip_bf16.h>

typedef _Float16 half8 __attribute__((ext_vector_type(8)));
typedef _Float16 half4v __attribute__((ext_vector_type(4)));
typedef float f32x4 __attribute__((ext_vector_type(4)));

#define BM 128
#define BK 64
#define LDK (BK + 8)   // 72 halfs = 144 B row stride: 16B-aligned b128 reads, 2-way bank alias (free)

// ---------------- W1 transpose + fp16 convert: W1[512][128] f32 -> W1T[128][512] f16 ----------
__global__ void prep_w1t(const float* __restrict__ W1, _Float16* __restrict__ W1T) {
    int idx = blockIdx.x * 256 + threadIdx.x;   // 65536 total
    int n = idx >> 9;          // 0..127
    int k = idx & 511;         // 0..511
    W1T[idx] = (_Float16)W1[k * 128 + n];
}

// ---------------- scores = tanh(x@W1 + b1)@W2 + b2 ------------------------------------------
__global__ __launch_bounds__(256) void score_kernel(
        const float* __restrict__ x, const _Float16* __restrict__ W1T,
        const float* __restrict__ b1, const float* __restrict__ W2,
        const float* __restrict__ b2, float* __restrict__ scores) {
    __shared__ _Float16 As[BM][LDK];
    __shared__ _Float16 Bs[128][LDK];
    const int tid = threadIdx.x;
    const int wave = tid >> 6, lane = tid & 63;
    const int quad = lane >> 4, col = lane & 15;
    const long row0 = (long)blockIdx.x * BM;

    f32x4 acc[2][8] = {};

    for (int kc = 0; kc < 512; kc += BK) {
        // stage A tile: 128 rows x 64 cols fp32 -> fp16 (8 float4 per thread)
        #pragma unroll
        for (int it = 0; it < 8; ++it) {
            int idx = it * 256 + tid;
            int r = idx >> 4, c4 = idx & 15;
            float4 v = *(const float4*)&x[(row0 + r) * 512 + kc + c4 * 4];
            half4v h; h[0] = (_Float16)v.x; h[1] = (_Float16)v.y;
                      h[2] = (_Float16)v.z; h[3] = (_Float16)v.w;
            *(half4v*)&As[r][c4 * 4] = h;
        }
        // stage B tile: W1T rows n=0..127, k-chunk (4 half8 per thread)
        #pragma unroll
        for (int it = 0; it < 4; ++it) {
            int idx = it * 256 + tid;
            int n = idx >> 3, c8 = idx & 7;
            *(half8*)&Bs[n][c8 * 8] = *(const half8*)&W1T[n * 512 + kc + c8 * 8];
        }
        __syncthreads();
        #pragma unroll
        for (int ks = 0; ks < BK; ks += 32) {
            half8 a[2], bf[8];
            #pragma unroll
            for (int mt = 0; mt < 2; ++mt)
                a[mt] = *(half8*)&As[wave * 32 + mt * 16 + col][ks + quad * 8];
            #pragma unroll
            for (int nt = 0; nt < 8; ++nt)
                bf[nt] = *(half8*)&Bs[nt * 16 + col][ks + quad * 8];
            #pragma unroll
            for (int mt = 0; mt < 2; ++mt)
                #pragma unroll
                for (int nt = 0; nt < 8; ++nt)
                    acc[mt][nt] = __builtin_amdgcn_mfma_f32_16x16x32_f16(
                        a[mt], bf[nt], acc[mt][nt], 0, 0, 0);
        }
        __syncthreads();
    }

    // epilogue: score[m] = sum_n tanh(h[m][n]) * W2[n] + b2
    float b1v[8], w2v[8];
    #pragma unroll
    for (int nt = 0; nt < 8; ++nt) {
        b1v[nt] = b1[nt * 16 + col];
        w2v[nt] = W2[nt * 16 + col];
    }
    float bias2 = b2[0];
    #pragma unroll
    for (int mt = 0; mt < 2; ++mt) {
        #pragma unroll
        for (int r = 0; r < 4; ++r) {
            float p = 0.f;
            #pragma unroll
            for (int nt = 0; nt < 8; ++nt)
                p += tanhf(acc[mt][nt][r] + b1v[nt]) * w2v[nt];
            // reduce across the 16 lanes of this quad (C/D: col=lane&15, row=quad*4+r)
            #pragma unroll
            for (int off = 1; off < 16; off <<= 1) p += __shfl_xor(p, off);
            if (col == 0)
                scores[row0 + wave * 32 + mt * 16 + quad * 4 + r] = p + bias2;
        }
    }
}

// ---------------- global max, two stages -----------------------------------------------------
__global__ void max_part(const float* __restrict__ scores, float* __restrict__ partial, int n) {
    __shared__ float red[256];
    int tid = threadIdx.x;
    float m = -1e30f;
    for (long i = (long)blockIdx.x * 256 + tid; i < n; i += (long)gridDim.x * 256)
        m = fmaxf(m, scores[i]);
    red[tid] = m; __syncthreads();
    for (int s = 128; s > 0; s >>= 1) {
        if (tid < s) red[tid] = fmaxf(red[tid], red[tid + s]);
        __syncthreads();
    }
    if (tid == 0) partial[blockIdx.x] = red[0];
}

__global__ void finalize_max(const float* __restrict__ partial, float* __restrict__ gmax,
                             float* __restrict__ denom, int nseg) {
    __shared__ float red[256];
    int tid = threadIdx.x;
    red[tid] = partial[tid]; __syncthreads();
    for (int s = 128; s > 0; s >>= 1) {
        if (tid < s) red[tid] = fmaxf(red[tid], red[tid + s]);
        __syncthreads();
    }
    if (tid == 0) gmax[0] = red[0];
    for (int b = tid; b < nseg; b += 256) denom[b] = 0.f;   // zero denoms (ws is poisoned)
}

// ---------------- exp + segment denominators (sorted batch -> wave segmented reduce) ---------
__global__ void exp_denom(float* __restrict__ scores, const int* __restrict__ batch,
                          const float* __restrict__ gmax, float* __restrict__ denom, int n) {
    const int lane = threadIdx.x & 63;
    const float gm = gmax[0];
    for (long i = (long)blockIdx.x * blockDim.x + threadIdx.x; i < n;
         i += (long)gridDim.x * blockDim.x) {
        int seg = batch[i];
        float e = __expf(scores[i] - gm);
        scores[i] = e;                      // exp_s in place
        float v = e;
        // segmented suffix-sum within the wave (batch sorted => runs are contiguous)
        #pragma unroll
        for (int off = 1; off < 64; off <<= 1) {
            float ov = __shfl_down(v, off);
            int   os = __shfl_down(seg, off);
            if (lane + off < 64 && os == seg) v += ov;
        }
        int pseg = __shfl_up(seg, 1);
        if (lane == 0 || pseg != seg) atomicAdd(&denom[seg], v);
    }
}

// ---------------- segment start offsets (batch sorted) ---------------------------------------
__global__ void seg_starts(const int* __restrict__ batch, int* __restrict__ starts,
                           int n, int nseg) {
    for (long i = (long)blockIdx.x * blockDim.x + threadIdx.x; i < n;
         i += (long)gridDim.x * blockDim.x) {
        int s = batch[i];
        int p = (i == 0) ? -1 : batch[i - 1];
        for (int b = p + 1; b <= s; ++b) starts[b] = (int)i;
        if (i == n - 1)
            for (int b = s + 1; b <= nseg; ++b) starts[b] = n;
    }
}

// ---------------- out[b] = sum_i weight_i * x_i, one block per segment ------------------------
// v2: 2 row-teams x 128 threads x float4 (16 B/lane) + unroll 4 for load-level parallelism.
// Theory: v1 (256 thr x float2, serial rows) was latency-bound (~8 KB in flight/CU vs the
// ~9-10 KB needed at ~900 cyc HBM latency). This gives 8x the outstanding bytes.
__global__ __launch_bounds__(256) void pool_kernel(
        const float* __restrict__ x, const float* __restrict__ exps,
        const float* __restrict__ denom, const int* __restrict__ starts,
        float* __restrict__ out) {
    __shared__ f32x4 red[128];
    const int b = blockIdx.x;
    const int s0 = starts[b], s1 = starts[b + 1];
    const float dinv = 1.f / (denom[b] + 1e-8f);
    const int team = threadIdx.x >> 7;      // 0/1: even/odd rows
    const int tl   = threadIdx.x & 127;
    const int c = tl * 4;                   // 128 threads x 4 cols = 512
    f32x4 acc = {0.f, 0.f, 0.f, 0.f};
    #pragma unroll 4
    for (int i = s0 + team; i < s1; i += 2) {
        float w = exps[i] * dinv;
        f32x4 xv = *(const f32x4*)&x[(long)i * 512 + c];
        acc += w * xv;
    }
    if (team) red[tl] = acc;
    __syncthreads();
    if (!team) {
        f32x4 o = red[tl];
        acc += o;
        *(f32x4*)&out[(long)b * 512 + c] = acc;
    }
}

extern "C" void kernel_launch(void* const* d_in, const int* in_sizes, int n_in,
                              void* d_out, int out_size, void* d_ws, size_t ws_size,
                              hipStream_t stream) {
    const float* x     = (const float*)d_in[0];
    const int*   batch = (const int*)d_in[1];
    const float* W1    = (const float*)d_in[2];
    const float* b1    = (const float*)d_in[3];
    const float* W2    = (const float*)d_in[4];
    const float* b2    = (const float*)d_in[5];
    float* out = (float*)d_out;

    const int N = in_sizes[1];          // 262144
    const int D = 512;
    const int NSEG = out_size / D;      // 1024

    // workspace layout (all 16B-aligned)
    _Float16* W1T   = (_Float16*)d_ws;                          // 128*512*2 = 131072 B
    float* scores   = (float*)((char*)d_ws + 131072);           // N floats (becomes exp_s)
    float* partial  = scores + N;                               // 256 floats
    float* gmax     = partial + 256;                            // 1 float (+pad)
    float* denom    = partial + 512;                            // NSEG floats
    int*   starts   = (int*)(denom + NSEG);                     // NSEG+1 ints

    prep_w1t<<<256, 256, 0, stream>>>(W1, W1T);
    seg_starts<<<256, 256, 0, stream>>>(batch, starts, N, NSEG);
    score_kernel<<<N / BM, 256, 0, stream>>>(x, W1T, b1, W2, b2, scores);
    max_part<<<256, 256, 0, stream>>>(scores, partial, N);
    finalize_max<<<1, 256, 0, stream>>>(partial, gmax, denom, NSEG);
    exp_denom<<<256, 256, 0, stream>>>(scores, batch, gmax, denom, N);
    pool_kernel<<<NSEG, 256, 0, stream>>>(x, scores, denom, starts, out);
}